// Round 3
// baseline (579.263 us; speedup 1.0000x reference)
//
#include <hip/hip_runtime.h>
#include <math.h>

// Problem constants (from reference)
constexpr int NQ    = 14;        // qubits
constexpr int DIM   = 16384;     // 2^14 state dim
constexpr int BATCH = 4;
constexpr int SEQ   = 2048;
constexpr int NPOS  = BATCH * SEQ;   // 8192 (b,s) positions
constexpr int P     = 4;             // positions per block
constexpr int TPB   = 256;           // threads per block

// native clang vector types — __builtin_nontemporal_store requires these
typedef float vf4 __attribute__((ext_vector_type(4)));
typedef float vf2 __attribute__((ext_vector_type(2)));

// Output is [B,S,DIM] where only d=0 of each (b,s) row is nonzero:
//   out[b,s,0] = total * softmax(z)[0]
// Two possible harness layouts, selected by out_size at launch:
//   CPLX=true : out_size = NPOS*2*DIM floats — complex64 viewed as (re,im) pairs
//   CPLX=false: out_size = NPOS*DIM   floats — float32 (real part only)
// Everything except d=0 must be zero-filled (harness poisons d_out each call).

template <bool CPLX>
__global__ void __launch_bounds__(TPB)
qenc_kernel(const float* __restrict__ x,     // [8192]
            const float* __restrict__ rot,   // [14,3]
            const float* __restrict__ ent,   // [13]
            const float* __restrict__ W1,    // [14]
            const float* __restrict__ b1,    // [14]
            const float* __restrict__ W2,    // [14,16384]
            const float* __restrict__ b2,    // [16384]
            float* __restrict__ out)
{
    __shared__ float sh_h[P * NQ];
    __shared__ float sh_tot_re, sh_tot_im;
    __shared__ float sh_z0[P];
    __shared__ float red[TPB];

    const int tid  = threadIdx.x;
    const long long pos0 = (long long)blockIdx.x * P;

    // --- per-block prologue: h = tanh(x*W1 + b1) for our P positions ---
    if (tid < P * NQ) {
        const int p = tid / NQ;
        const int k = tid - p * NQ;
        sh_h[tid] = tanhf(x[pos0 + p] * W1[k] + b1[k]);
    }
    // total = prod(rot_factors) * prod(ent_factors) — one thread in wave 1
    if (tid == 64) {
        float tre = 1.0f, tim = 0.0f;
        for (int q = 0; q < NQ; ++q) {
            const float a0 = 0.5f * rot[q * 3 + 0];
            const float a1 = 0.5f * rot[q * 3 + 1];
            const float a2 = 0.5f * rot[q * 3 + 2];
            const float fre = cosf(a0) * cosf(a1) * cosf(a2);
            const float fim = sinf(a0) * sinf(a1) * sinf(a2);
            const float nre = tre * fre - tim * fim;
            const float nim = tre * fim + tim * fre;
            tre = nre; tim = nim;
        }
        for (int q = 0; q < NQ - 1; ++q) {
            const float cs  = 1.0f / (1.0f + __expf(-ent[q]));
            const float nre = tre * cs - tim * (1.0f - cs);
            const float nim = tre * (1.0f - cs) + tim * cs;
            tre = nre; tim = nim;
        }
        sh_tot_re = tre; sh_tot_im = tim;
    }
    __syncthreads();

    float h[P][NQ];
#pragma unroll
    for (int p = 0; p < P; ++p)
#pragma unroll
        for (int k = 0; k < NQ; ++k)
            h[p][k] = sh_h[p * NQ + k];

    float acc[P];
#pragma unroll
    for (int p = 0; p < P; ++p) acc[p] = 0.0f;

    // z is small (|z| <~ 2: |h|<=1, W2 ~ N(0,0.01)) so plain exp-sum is fine
    // (the reference's max-subtraction cancels exactly in the d=0 ratio).
    if constexpr (CPLX) {
        // 2 consecutive d per thread per iter -> one 16B zero store (re,im pairs)
        constexpr int ITERS = DIM / (2 * TPB);   // 32
        for (int i = 0; i < ITERS; ++i) {
            const int d = 2 * (tid + TPB * i);
            float2 wv[NQ];
#pragma unroll
            for (int k = 0; k < NQ; ++k)
                wv[k] = *reinterpret_cast<const float2*>(W2 + (size_t)k * DIM + d);
            const float2 bb = *reinterpret_cast<const float2*>(b2 + d);
            const bool d0 = (d == 0);   // only tid==0, i==0
#pragma unroll
            for (int p = 0; p < P; ++p) {
                float za = bb.x, zb = bb.y;
#pragma unroll
                for (int k = 0; k < NQ; ++k) {
                    za = fmaf(h[p][k], wv[k].x, za);
                    zb = fmaf(h[p][k], wv[k].y, zb);
                }
                acc[p] += __expf(za) + __expf(zb);

                float* rowp = out + (size_t)(pos0 + p) * (2 * (size_t)DIM) + 2 * d;
                if (!d0) {
                    vf4 z4 = {0.f, 0.f, 0.f, 0.f};
                    __builtin_nontemporal_store(z4, reinterpret_cast<vf4*>(rowp));
                } else {
                    sh_z0[p] = za;   // leave d=0 pair for the epilogue
                    vf2 z2 = {0.f, 0.f};
                    __builtin_nontemporal_store(z2, reinterpret_cast<vf2*>(rowp + 2));
                }
            }
        }
    } else {
        // 4 consecutive d per thread per iter -> one 16B zero store (real only)
        constexpr int ITERS = DIM / (4 * TPB);   // 16
        for (int i = 0; i < ITERS; ++i) {
            const int d = 4 * (tid + TPB * i);
            float4 wv[NQ];
#pragma unroll
            for (int k = 0; k < NQ; ++k)
                wv[k] = *reinterpret_cast<const float4*>(W2 + (size_t)k * DIM + d);
            const float4 bb = *reinterpret_cast<const float4*>(b2 + d);
            const bool d0 = (d == 0);   // only tid==0, i==0
#pragma unroll
            for (int p = 0; p < P; ++p) {
                float za = bb.x, zb = bb.y, zc = bb.z, zd = bb.w;
#pragma unroll
                for (int k = 0; k < NQ; ++k) {
                    za = fmaf(h[p][k], wv[k].x, za);
                    zb = fmaf(h[p][k], wv[k].y, zb);
                    zc = fmaf(h[p][k], wv[k].z, zc);
                    zd = fmaf(h[p][k], wv[k].w, zd);
                }
                acc[p] += (__expf(za) + __expf(zb)) + (__expf(zc) + __expf(zd));

                float* rowp = out + (size_t)(pos0 + p) * (size_t)DIM + d;
                if (!d0) {
                    vf4 z4 = {0.f, 0.f, 0.f, 0.f};
                    __builtin_nontemporal_store(z4, reinterpret_cast<vf4*>(rowp));
                } else {
                    sh_z0[p] = za;   // leave element 0 for the epilogue
                    __builtin_nontemporal_store(0.f, rowp + 1);
                    __builtin_nontemporal_store(0.f, rowp + 2);
                    __builtin_nontemporal_store(0.f, rowp + 3);
                }
            }
        }
    }

    // --- block reduction of softmax denominators + final writes ---
#pragma unroll
    for (int p = 0; p < P; ++p) {
        __syncthreads();
        red[tid] = acc[p];
        __syncthreads();
        for (int s = TPB / 2; s > 0; s >>= 1) {
            if (tid < s) red[tid] += red[tid + s];
            __syncthreads();
        }
        if (tid == 0) {
            const float w0 = __expf(sh_z0[p]) / red[0];
            const size_t stride = CPLX ? 2 * (size_t)DIM : (size_t)DIM;
            float* rowp = out + (size_t)(pos0 + p) * stride;
            rowp[0] = sh_tot_re * w0;
            if constexpr (CPLX) rowp[1] = sh_tot_im * w0;
        }
    }
}

extern "C" void kernel_launch(void* const* d_in, const int* in_sizes, int n_in,
                              void* d_out, int out_size, void* d_ws, size_t ws_size,
                              hipStream_t stream) {
    (void)in_sizes; (void)n_in; (void)d_ws; (void)ws_size;
    const float* x   = (const float*)d_in[0];
    const float* rot = (const float*)d_in[1];
    const float* ent = (const float*)d_in[2];
    const float* W1  = (const float*)d_in[3];
    const float* b1  = (const float*)d_in[4];
    const float* W2  = (const float*)d_in[5];
    const float* b2  = (const float*)d_in[6];
    float* out = (float*)d_out;

    const long long cplx_elems = (long long)NPOS * 2LL * DIM;  // 268,435,456
    if ((long long)out_size >= cplx_elems) {
        qenc_kernel<true><<<NPOS / P, TPB, 0, stream>>>(x, rot, ent, W1, b1, W2, b2, out);
    } else {
        // out_size == NPOS*DIM: float32 output (real part only)
        qenc_kernel<false><<<NPOS / P, TPB, 0, stream>>>(x, rot, ent, W1, b1, W2, b2, out);
    }
}

// Round 4
// 567.008 us; speedup vs baseline: 1.0216x; 1.0216x over previous
//
#include <hip/hip_runtime.h>
#include <math.h>

// Problem constants (from reference)
constexpr int NQ    = 14;        // qubits
constexpr int DIM   = 16384;     // 2^14 state dim
constexpr int BATCH = 4;
constexpr int SEQ   = 2048;
constexpr int NPOS  = BATCH * SEQ;   // 8192 (b,s) positions
constexpr int P     = 4;             // positions per block
constexpr int TPB   = 256;           // threads per block

// native clang vector types — __builtin_nontemporal_store requires these
typedef float vf4 __attribute__((ext_vector_type(4)));
typedef float vf2 __attribute__((ext_vector_type(2)));

// block-uniform float -> SGPR (readfirstlane marks the value uniform)
__device__ __forceinline__ float uniform_f(float v) {
    return __int_as_float(__builtin_amdgcn_readfirstlane(__float_as_int(v)));
}

// Output is [B,S,DIM] where only d=0 of each (b,s) row is nonzero:
//   out[b,s,0] = total * softmax(z)[0],  z = tanh(x*W1+b1) @ W2 + b2
// CPLX=true : out_size = NPOS*2*DIM floats (complex64 as re,im pairs) — the
//             layout the harness actually uses (verified passing in R3).
// CPLX=false: out_size = NPOS*DIM floats (real only) — kept as fallback.
// Everything except d=0 must be zero-filled (harness poisons d_out each call).

template <bool CPLX>
__global__ void __launch_bounds__(TPB)
qenc_kernel(const float* __restrict__ x,     // [8192]
            const float* __restrict__ rot,   // [14,3]
            const float* __restrict__ ent,   // [13]
            const float* __restrict__ W1,    // [14]
            const float* __restrict__ b1,    // [14]
            const float* __restrict__ W2,    // [14,16384]
            const float* __restrict__ b2,    // [16384]
            float* __restrict__ out)
{
    __shared__ float sh_h[P * NQ];
    __shared__ float sh_tot_re, sh_tot_im;
    __shared__ float sh_z0[P];
    __shared__ float red[4][P];   // 4 waves x P partial denominators

    const int tid  = threadIdx.x;
    const int wid  = tid >> 6;
    const int lane = tid & 63;
    const long long pos0 = (long long)blockIdx.x * P;

    // --- prologue: h = tanh(x*W1 + b1) for our P positions (wave 0) ---
    if (tid < P * NQ) {
        const int p = tid / NQ;
        const int k = tid - p * NQ;
        sh_h[tid] = tanhf(x[pos0 + p] * W1[k] + b1[k]);
    }
    // total = prod(rot_factors) * prod(ent_factors) — one thread in wave 1
    if (tid == 64) {
        float tre = 1.0f, tim = 0.0f;
        for (int q = 0; q < NQ; ++q) {
            const float a0 = 0.5f * rot[q * 3 + 0];
            const float a1 = 0.5f * rot[q * 3 + 1];
            const float a2 = 0.5f * rot[q * 3 + 2];
            const float fre = cosf(a0) * cosf(a1) * cosf(a2);
            const float fim = sinf(a0) * sinf(a1) * sinf(a2);
            const float nre = tre * fre - tim * fim;
            const float nim = tre * fim + tim * fre;
            tre = nre; tim = nim;
        }
        for (int q = 0; q < NQ - 1; ++q) {
            const float cs  = 1.0f / (1.0f + __expf(-ent[q]));
            const float nre = tre * cs - tim * (1.0f - cs);
            const float nim = tre * (1.0f - cs) + tim * cs;
            tre = nre; tim = nim;
        }
        sh_tot_re = tre; sh_tot_im = tim;
    }
    __syncthreads();

    // h is block-uniform: pull into SGPRs so the 14x4 values don't eat VGPRs
    float h[P][NQ];
#pragma unroll
    for (int p = 0; p < P; ++p)
#pragma unroll
        for (int k = 0; k < NQ; ++k)
            h[p][k] = uniform_f(sh_h[p * NQ + k]);

    float acc[P];
#pragma unroll
    for (int p = 0; p < P; ++p) acc[p] = 0.0f;

    // --- main loop: 4 consecutive d per thread per iter (float4 W2 loads) ---
    // |z| <~ 1.2 (|h|<=1, W2 ~ N(0,0.01)) so plain exp-sum is numerically fine
    // (the reference's max-subtraction cancels exactly in the d=0 ratio).
    constexpr int ITERS = DIM / (4 * TPB);   // 16
    for (int i = 0; i < ITERS; ++i) {
        const int d = 4 * (tid + TPB * i);
        float4 wv[NQ];
#pragma unroll
        for (int k = 0; k < NQ; ++k)
            wv[k] = *reinterpret_cast<const float4*>(W2 + (size_t)k * DIM + d);
        const float4 bb = *reinterpret_cast<const float4*>(b2 + d);
        const bool d0 = (d == 0);   // only tid==0, i==0
#pragma unroll
        for (int p = 0; p < P; ++p) {
            float za = bb.x, zb = bb.y, zc = bb.z, zd = bb.w;
#pragma unroll
            for (int k = 0; k < NQ; ++k) {
                za = fmaf(h[p][k], wv[k].x, za);
                zb = fmaf(h[p][k], wv[k].y, zb);
                zc = fmaf(h[p][k], wv[k].z, zc);
                zd = fmaf(h[p][k], wv[k].w, zd);
            }
            acc[p] += (__expf(za) + __expf(zb)) + (__expf(zc) + __expf(zd));

            if constexpr (CPLX) {
                float* rowp = out + (size_t)(pos0 + p) * (2 * (size_t)DIM) + 2 * d;
                vf4 z4 = {0.f, 0.f, 0.f, 0.f};
                if (!d0) {
                    __builtin_nontemporal_store(z4, reinterpret_cast<vf4*>(rowp));
                    __builtin_nontemporal_store(z4, reinterpret_cast<vf4*>(rowp + 4));
                } else {
                    sh_z0[p] = za;   // leave (re,im) of d=0 for the epilogue
                    vf2 z2 = {0.f, 0.f};
                    __builtin_nontemporal_store(z2, reinterpret_cast<vf2*>(rowp + 2));
                    __builtin_nontemporal_store(z4, reinterpret_cast<vf4*>(rowp + 4));
                }
            } else {
                float* rowp = out + (size_t)(pos0 + p) * (size_t)DIM + d;
                if (!d0) {
                    vf4 z4 = {0.f, 0.f, 0.f, 0.f};
                    __builtin_nontemporal_store(z4, reinterpret_cast<vf4*>(rowp));
                } else {
                    sh_z0[p] = za;
                    __builtin_nontemporal_store(0.f, rowp + 1);
                    __builtin_nontemporal_store(0.f, rowp + 2);
                    __builtin_nontemporal_store(0.f, rowp + 3);
                }
            }
        }
    }

    // --- reduction: wave shuffle, then 4 partials per p in LDS ---
#pragma unroll
    for (int p = 0; p < P; ++p) {
        float v = acc[p];
#pragma unroll
        for (int off = 32; off > 0; off >>= 1)
            v += __shfl_down(v, off, 64);
        if (lane == 0) red[wid][p] = v;
    }
    __syncthreads();
    if (tid < P) {
        const float denom = (red[0][tid] + red[1][tid]) + (red[2][tid] + red[3][tid]);
        const float w0 = __expf(sh_z0[tid]) / denom;
        const size_t stride = CPLX ? 2 * (size_t)DIM : (size_t)DIM;
        float* rowp = out + (size_t)(pos0 + tid) * stride;
        rowp[0] = sh_tot_re * w0;
        if constexpr (CPLX) rowp[1] = sh_tot_im * w0;
    }
}

extern "C" void kernel_launch(void* const* d_in, const int* in_sizes, int n_in,
                              void* d_out, int out_size, void* d_ws, size_t ws_size,
                              hipStream_t stream) {
    (void)in_sizes; (void)n_in; (void)d_ws; (void)ws_size;
    const float* x   = (const float*)d_in[0];
    const float* rot = (const float*)d_in[1];
    const float* ent = (const float*)d_in[2];
    const float* W1  = (const float*)d_in[3];
    const float* b1  = (const float*)d_in[4];
    const float* W2  = (const float*)d_in[5];
    const float* b2  = (const float*)d_in[6];
    float* out = (float*)d_out;

    const long long cplx_elems = (long long)NPOS * 2LL * DIM;  // 268,435,456
    if ((long long)out_size >= cplx_elems) {
        qenc_kernel<true><<<NPOS / P, TPB, 0, stream>>>(x, rot, ent, W1, b1, W2, b2, out);
    } else {
        qenc_kernel<false><<<NPOS / P, TPB, 0, stream>>>(x, rot, ent, W1, b1, W2, b2, out);
    }
}